// Round 6
// baseline (250.251 us; speedup 1.0000x reference)
//
#include <hip/hip_runtime.h>
#include <hip/hip_bf16.h>

typedef __attribute__((ext_vector_type(8))) short short8;
typedef __attribute__((ext_vector_type(4))) float f32x4;
typedef unsigned short u16;
typedef unsigned int u32;
typedef unsigned long long u64;

typedef u64    __attribute__((may_alias)) u64a;
typedef short8 __attribute__((may_alias)) short8a;
typedef float4 __attribute__((may_alias)) float4a;

#define Tseq 4096

__device__ __forceinline__ u32 pk_bf(float a, float b) {
    union { __hip_bfloat162 h; u32 u; } t;
    float2 f; f.x = a; f.y = b;
    t.h = __float22bfloat162_rn(f);
    return t.u;
}

__device__ __forceinline__ u16 f2bf(float f) {
    u32 u = __float_as_uint(f);
    u = (u + 0x7FFFu + ((u >> 16) & 1u)) >> 16;
    return (u16)u;
}

__device__ __forceinline__ short8 cvt8(float4 a, float4 b) {
    union { short8 s; u32 u[4]; } t;
    t.u[0] = pk_bf(a.x, a.y); t.u[1] = pk_bf(a.z, a.w);
    t.u[2] = pk_bf(b.x, b.y); t.u[3] = pk_bf(b.z, b.w);
    return t.s;
}

__device__ __forceinline__ void gld_lds16(const void* g, void* l) {
    __builtin_amdgcn_global_load_lds(
        (const __attribute__((address_space(1))) u32*)g,
        (__attribute__((address_space(3))) u32*)l, 16, 0, 0);
}

// ---- W -> fragment-major bf16 (B-operand layout), 1/sqrt(C) folded into Wq ----
__global__ __launch_bounds__(256) void wt_kernel(const float* __restrict__ Wq,
                                                 const float* __restrict__ Wk,
                                                 const float* __restrict__ Wv,
                                                 u16* __restrict__ wtf) {
    int idx = blockIdx.x * 256 + threadIdx.x;
    int lane = idx & 63, cc = (idx >> 6) & 31, n = (idx >> 11) & 3, mat = idx >> 13;
    const float* W = (mat == 0) ? Wq : ((mat == 1) ? Wk : Wv);
    float sc = (mat == 0) ? 0.03125f : 1.0f;
    int h = n * 16 + (lane & 15);
    int cbase = cc * 32 + (lane >> 4) * 8;
    union { short8 s; u32 u[4]; } t;
#pragma unroll
    for (int j2 = 0; j2 < 4; ++j2) {
        float a = W[(size_t)(cbase + j2 * 2)     * 64 + h] * sc;
        float b = W[(size_t)(cbase + j2 * 2 + 1) * 64 + h] * sc;
        t.u[j2] = pk_bf(a, b);
    }
    *(short8a*)(wtf + (size_t)idx * 8) = t.s;
}

// ---- QKV projection: async-LDS W staging (double-buffered), x reg pipeline ----
__global__ __launch_bounds__(256, 2) void proj_kernel(const float* __restrict__ x,
                                                      const u16* __restrict__ wtf,
                                                      u16* __restrict__ qb,
                                                      u16* __restrict__ kA,
                                                      u16* __restrict__ vA) {
    // phase = 2 cc's; buf = 12 mn x 2 ccp x 64 lanes x 8 u16 = 24 KiB
    __shared__ __align__(16) u16 Wl[2][12 * 2 * 64 * 8];

    const int tid = threadIdx.x, lane = tid & 63, wave = tid >> 6;
    const int m = lane & 15, quad = lane >> 4;
    const long rowbase = (long)blockIdx.x * 64 + wave * 16;
    const float* xr = x + (rowbase + m) * 1024 + quad * 8;

    f32x4 acc[12];
#pragma unroll
    for (int i = 0; i < 12; ++i) acc[i] = (f32x4){0.f, 0.f, 0.f, 0.f};

    // stage phase p into Wl[buf]: 24 chunks of 1 KiB; this wave does 6
#define STAGE(p, buf)                                                          \
    {                                                                          \
        _Pragma("unroll")                                                      \
        for (int i = 0; i < 6; ++i) {                                          \
            int c = wave * 6 + i, mn = c >> 1, ccp = c & 1;                    \
            const u16* g = wtf + ((size_t)(mn * 32 + (p) * 2 + ccp) * 64 + lane) * 8; \
            u16* l = &Wl[buf][(size_t)(mn * 2 + ccp) * 512];                   \
            gld_lds16(g, l);                                                   \
        }                                                                      \
    }

    float4 xa[4], xb[4];
#pragma unroll
    for (int t = 0; t < 4; ++t)
        xa[t] = *(const float4a*)(xr + (t >> 1) * 32 + (t & 1) * 4);
#pragma unroll
    for (int t = 0; t < 4; ++t)
        xb[t] = *(const float4a*)(xr + (2 + (t >> 1)) * 32 + (t & 1) * 4);

    STAGE(0, 0);
    __syncthreads();

    for (int p = 0; p < 16; ++p) {
        if (p < 15) STAGE(p + 1, (p + 1) & 1);
        float4 xn[4];
        if (p < 14) {
#pragma unroll
            for (int t = 0; t < 4; ++t)
                xn[t] = *(const float4a*)(xr + (2 * (p + 2) + (t >> 1)) * 32 + (t & 1) * 4);
        }
        const u16* wb = Wl[p & 1];
#pragma unroll
        for (int ccp = 0; ccp < 2; ++ccp) {
            short8 af = cvt8(xa[ccp * 2], xa[ccp * 2 + 1]);
#pragma unroll
            for (int mn = 0; mn < 12; ++mn) {
                short8 bf = *(const short8a*)(wb + ((size_t)(mn * 2 + ccp) * 64 + lane) * 8);
                acc[mn] = __builtin_amdgcn_mfma_f32_16x16x32_bf16(af, bf, acc[mn], 0, 0, 0);
            }
        }
#pragma unroll
        for (int t = 0; t < 4; ++t) { xa[t] = xb[t]; if (p < 14) xb[t] = xn[t]; }
        __syncthreads();
    }
#undef STAGE

    const int b  = (int)(rowbase >> 12);
    const int tb = (int)(rowbase & 4095);

    // q: natural [t][h]
#pragma unroll
    for (int n = 0; n < 4; ++n)
#pragma unroll
        for (int r = 0; r < 4; ++r)
            qb[(rowbase + quad * 4 + r) * 64 + n * 16 + m] = f2bf(acc[n][r]);

    // kA[b][key>>4][h>>5][(key&15)+16*((h>>3)&3)][h&7]
#pragma unroll
    for (int n = 0; n < 4; ++n) {
        int kk = n >> 1;
        int lq = (n * 2 + (m >> 3)) & 3;
        int j  = m & 7;
#pragma unroll
        for (int r = 0; r < 4; ++r) {
            int key = tb + quad * 4 + r;
            size_t a = ((((size_t)b * 256 + (key >> 4)) * 2 + kk) * 64
                        + ((key & 15) + 16 * lq)) * 8 + j;
            kA[a] = f2bf(acc[4 + n][r]);
        }
    }

    // vA[b][h>>4][key>>5][(h&15)+16*((key>>3)&3)][key&7]
    {
        int key0 = tb + quad * 4;
        int j0 = key0 & 7;
        int q2 = (key0 >> 3) & 3;
        int kc = key0 >> 5;
#pragma unroll
        for (int n = 0; n < 4; ++n) {
            u64 pv = (u64)pk_bf(acc[8 + n][0], acc[8 + n][1])
                   | ((u64)pk_bf(acc[8 + n][2], acc[8 + n][3]) << 32);
            size_t a = ((((size_t)b * 4 + n) * 128 + kc) * 64 + (m + 16 * q2)) * 8 + j0;
            *(u64a*)(vA + a) = pv;
        }
    }
}

// ---- attention: one 32-row strip per block, 4-way split-K, in-register P ----
// Same structure as R5 except the P redistribution (QK^T output -> PV B-operand)
// is done with permlane swaps instead of an LDS write/barrier/read roundtrip.
// Derivation: per row-group m, the 4 quad-lanes hold a 4x4 matrix of u64s
// M[qs][mt] (pv_mt = packed bf16 of keys mt*16+qs*4+0..3). The PV B-fragment
// needs lane (m,quad) to hold {M[2(q&1)][q>>1], M[2(q&1)+1][q>>1]} (pf0) and
// the same with col+2 (pf1). With A=(pv0,pv2), B=(pv1,pv3) per lane:
//   v_permlane32_swap A,B  (upper-32 A <-> lower-32 B)
//   v_permlane16_swap A,B  (odd-16 A  <-> even-16 B)
// then pf0 = {A0,A1,B0,B1}, pf1 = {A2,A3,B2,B3}. Bit-identical P values.
struct K8 { short8 k[8]; };

__device__ __forceinline__ void loadK(K8& f, const u16* kAb, int kt, int lane) {
    const u16* kp = kAb + (size_t)kt * 4096 + (size_t)lane * 8;
#pragma unroll
    for (int mt = 0; mt < 4; ++mt) {
        f.k[mt * 2]     = *(const short8a*)(kp + mt * 1024);
        f.k[mt * 2 + 1] = *(const short8a*)(kp + mt * 1024 + 512);
    }
}

__device__ __forceinline__ void loadV(short8* vf, const u16* vAb, int kt, int lane) {
    const u16* vp = vAb + (size_t)kt * 1024 + (size_t)lane * 8;
#pragma unroll
    for (int ht = 0; ht < 4; ++ht) {
        vf[ht * 2]     = *(const short8a*)(vp + (size_t)ht * 65536);
        vf[ht * 2 + 1] = *(const short8a*)(vp + (size_t)ht * 65536 + 512);
    }
}

// QK^T + mask + fixed-max softmax + in-register transpose -> pf0/pf1
__device__ __forceinline__ void qk_p(const K8& f, short8 qf0, short8 qf1,
        float& lsum, int kt, int n_s, int qrow, int quad, int m,
        short8& pf0, short8& pf1) {
    const float L2E = 1.4426950408889634f;
    const float FMB = 4.0f * L2E;
    f32x4 s[4];
    __builtin_amdgcn_s_setprio(1);
#pragma unroll
    for (int mt = 0; mt < 4; ++mt) {
        f32x4 a = (f32x4){0.f, 0.f, 0.f, 0.f};
        a = __builtin_amdgcn_mfma_f32_16x16x32_bf16(f.k[mt * 2],     qf0, a, 0, 0, 0);
        a = __builtin_amdgcn_mfma_f32_16x16x32_bf16(f.k[mt * 2 + 1], qf1, a, 0, 0, 0);
        s[mt] = a;
    }
    __builtin_amdgcn_s_setprio(0);
    if (kt == n_s) {
#pragma unroll
        for (int mt = 0; mt < 4; ++mt)
#pragma unroll
            for (int r = 0; r < 4; ++r) {
                int key = kt * 64 + mt * 16 + quad * 4 + r;
                if (key > qrow) s[mt][r] = -1e30f;
            }
    }
    float p[4][4];
#pragma unroll
    for (int mt = 0; mt < 4; ++mt) {
        p[mt][0] = __builtin_amdgcn_exp2f(s[mt][0] * L2E - FMB);
        p[mt][1] = __builtin_amdgcn_exp2f(s[mt][1] * L2E - FMB);
        p[mt][2] = __builtin_amdgcn_exp2f(s[mt][2] * L2E - FMB);
        p[mt][3] = __builtin_amdgcn_exp2f(s[mt][3] * L2E - FMB);
        lsum += (p[mt][0] + p[mt][1]) + (p[mt][2] + p[mt][3]);
    }
    // A = (pv0, pv2), B = (pv1, pv3) as u32s
    u32 A0 = pk_bf(p[0][0], p[0][1]), A1 = pk_bf(p[0][2], p[0][3]);
    u32 B0 = pk_bf(p[1][0], p[1][1]), B1 = pk_bf(p[1][2], p[1][3]);
    u32 A2 = pk_bf(p[2][0], p[2][1]), A3 = pk_bf(p[2][2], p[2][3]);
    u32 B2 = pk_bf(p[3][0], p[3][1]), B3 = pk_bf(p[3][2], p[3][3]);
    asm volatile("v_permlane32_swap_b32 %0, %1" : "+v"(A0), "+v"(B0));
    asm volatile("v_permlane32_swap_b32 %0, %1" : "+v"(A1), "+v"(B1));
    asm volatile("v_permlane32_swap_b32 %0, %1" : "+v"(A2), "+v"(B2));
    asm volatile("v_permlane32_swap_b32 %0, %1" : "+v"(A3), "+v"(B3));
    asm volatile("v_permlane16_swap_b32 %0, %1" : "+v"(A0), "+v"(B0));
    asm volatile("v_permlane16_swap_b32 %0, %1" : "+v"(A1), "+v"(B1));
    asm volatile("v_permlane16_swap_b32 %0, %1" : "+v"(A2), "+v"(B2));
    asm volatile("v_permlane16_swap_b32 %0, %1" : "+v"(A3), "+v"(B3));
    union { short8 s; u32 u[4]; } t0, t1;
    t0.u[0] = A0; t0.u[1] = A1; t0.u[2] = B0; t0.u[3] = B1;
    t1.u[0] = A2; t1.u[1] = A3; t1.u[2] = B2; t1.u[3] = B3;
    pf0 = t0.s; pf1 = t1.s;
}

__global__ __launch_bounds__(256, 3) void attn_kernel(const u16* __restrict__ qb,
                                                      const u16* __restrict__ kA,
                                                      const u16* __restrict__ vA,
                                                      float* __restrict__ out) {
    __shared__ float PubA[3][16][64];                  // 12 KiB
    __shared__ float PubB[3][16][64];                  // 12 KiB
    __shared__ float LA[3][64], LB[3][64];             // 1.5 KiB

    const int tid = threadIdx.x, lane = tid & 63, wave = tid >> 6;
    const int m = lane & 15, quad = lane >> 4;
    const int beta = blockIdx.x;
    const int b = beta & 7;                 // XCD affinity: one batch per XCD
    const int u = beta >> 3;                // 0..127 within XCD
    // serpentine rank: CU c gets ranks c, 63-c, 64+c, 127-c (sum 130/132)
    const int kseg = u >> 5, c = u & 31;
    const int rho = (kseg & 1) ? (kseg * 32 + 31 - c) : (kseg * 32 + c);
    const int n_s = 63 - (rho >> 1);        // diagonal 64-key tile
    const int T = n_s + 1;
    const int g = n_s * 2 + (rho & 1);      // 32-row strip index, 0..127
    const int qbase = g * 32;

    // split-K: wave = part; contiguous, lengths differ by <=1
    const int kt0 = wave * T / 4;
    const int kt1 = (wave + 1) * T / 4 - 1; // inclusive; only wave 3 hits n_s

    const u16* qpA = qb + ((size_t)b * Tseq + qbase + m) * 64;
    const u16* qpB = qpA + 16 * 64;
    short8 qA0 = *(const short8a*)(qpA + quad * 8);
    short8 qA1 = *(const short8a*)(qpA + 32 + quad * 8);
    short8 qB0 = *(const short8a*)(qpB + quad * 8);
    short8 qB1 = *(const short8a*)(qpB + 32 + quad * 8);

    const u16* kAb = kA + (size_t)b * (256 * 2 * 64 * 8);
    const u16* vAb = vA + (size_t)b * (4 * 128 * 64 * 8);

    f32x4 oA[4], oB[4];
#pragma unroll
    for (int ht = 0; ht < 4; ++ht) {
        oA[ht] = (f32x4){0.f, 0.f, 0.f, 0.f};
        oB[ht] = (f32x4){0.f, 0.f, 0.f, 0.f};
    }
    float lsA = 0.f, lsB = 0.f;
    const int qrowA = qbase + m;
    const int qrowB = qbase + 16 + m;

    if (kt0 <= kt1) {
        K8 ka;
        short8 vf[8];
        loadK(ka, kAb, kt0, lane);
        for (int kt = kt0;; ++kt) {
            loadV(vf, vAb, kt, lane);        // early: consumed after 2 softmaxes
            short8 pA0, pA1, pB0, pB1;
            qk_p(ka, qA0, qA1, lsA, kt, n_s, qrowA, quad, m, pA0, pA1);
            qk_p(ka, qB0, qB1, lsB, kt, n_s, qrowB, quad, m, pB0, pB1);
            if (kt < kt1) loadK(ka, kAb, kt + 1, lane);  // after last ka read
            __builtin_amdgcn_s_setprio(1);
            oA[0] = __builtin_amdgcn_mfma_f32_16x16x32_bf16(vf[0], pA0, oA[0], 0, 0, 0);
            oA[0] = __builtin_amdgcn_mfma_f32_16x16x32_bf16(vf[1], pA1, oA[0], 0, 0, 0);
            oA[1] = __builtin_amdgcn_mfma_f32_16x16x32_bf16(vf[2], pA0, oA[1], 0, 0, 0);
            oA[1] = __builtin_amdgcn_mfma_f32_16x16x32_bf16(vf[3], pA1, oA[1], 0, 0, 0);
            oA[2] = __builtin_amdgcn_mfma_f32_16x16x32_bf16(vf[4], pA0, oA[2], 0, 0, 0);
            oA[2] = __builtin_amdgcn_mfma_f32_16x16x32_bf16(vf[5], pA1, oA[2], 0, 0, 0);
            oA[3] = __builtin_amdgcn_mfma_f32_16x16x32_bf16(vf[6], pA0, oA[3], 0, 0, 0);
            oA[3] = __builtin_amdgcn_mfma_f32_16x16x32_bf16(vf[7], pA1, oA[3], 0, 0, 0);
            oB[0] = __builtin_amdgcn_mfma_f32_16x16x32_bf16(vf[0], pB0, oB[0], 0, 0, 0);
            oB[0] = __builtin_amdgcn_mfma_f32_16x16x32_bf16(vf[1], pB1, oB[0], 0, 0, 0);
            oB[1] = __builtin_amdgcn_mfma_f32_16x16x32_bf16(vf[2], pB0, oB[1], 0, 0, 0);
            oB[1] = __builtin_amdgcn_mfma_f32_16x16x32_bf16(vf[3], pB1, oB[1], 0, 0, 0);
            oB[2] = __builtin_amdgcn_mfma_f32_16x16x32_bf16(vf[4], pB0, oB[2], 0, 0, 0);
            oB[2] = __builtin_amdgcn_mfma_f32_16x16x32_bf16(vf[5], pB1, oB[2], 0, 0, 0);
            oB[3] = __builtin_amdgcn_mfma_f32_16x16x32_bf16(vf[6], pB0, oB[3], 0, 0, 0);
            oB[3] = __builtin_amdgcn_mfma_f32_16x16x32_bf16(vf[7], pB1, oB[3], 0, 0, 0);
            __builtin_amdgcn_s_setprio(0);
            if (kt == kt1) break;
        }
    }

    // merge: wave0 finalizes substrip A, wave1 substrip B; fixed-max softmax
    // makes partials pure adds. Publish slots: A from waves 1,2,3; B from 0,2,3.
    if (wave == 0) {
#pragma unroll
        for (int ht = 0; ht < 4; ++ht) {
            PubB[0][ht * 4 + 0][lane] = oB[ht][0];
            PubB[0][ht * 4 + 1][lane] = oB[ht][1];
            PubB[0][ht * 4 + 2][lane] = oB[ht][2];
            PubB[0][ht * 4 + 3][lane] = oB[ht][3];
        }
        LB[0][lane] = lsB;
    } else if (wave == 1) {
#pragma unroll
        for (int ht = 0; ht < 4; ++ht) {
            PubA[0][ht * 4 + 0][lane] = oA[ht][0];
            PubA[0][ht * 4 + 1][lane] = oA[ht][1];
            PubA[0][ht * 4 + 2][lane] = oA[ht][2];
            PubA[0][ht * 4 + 3][lane] = oA[ht][3];
        }
        LA[0][lane] = lsA;
    } else if (wave == 2) {
#pragma unroll
        for (int ht = 0; ht < 4; ++ht) {
            PubA[1][ht * 4 + 0][lane] = oA[ht][0];
            PubA[1][ht * 4 + 1][lane] = oA[ht][1];
            PubA[1][ht * 4 + 2][lane] = oA[ht][2];
            PubA[1][ht * 4 + 3][lane] = oA[ht][3];
            PubB[1][ht * 4 + 0][lane] = oB[ht][0];
            PubB[1][ht * 4 + 1][lane] = oB[ht][1];
            PubB[1][ht * 4 + 2][lane] = oB[ht][2];
            PubB[1][ht * 4 + 3][lane] = oB[ht][3];
        }
        LA[1][lane] = lsA;
        LB[1][lane] = lsB;
    } else {
#pragma unroll
        for (int ht = 0; ht < 4; ++ht) {
            PubA[2][ht * 4 + 0][lane] = oA[ht][0];
            PubA[2][ht * 4 + 1][lane] = oA[ht][1];
            PubA[2][ht * 4 + 2][lane] = oA[ht][2];
            PubA[2][ht * 4 + 3][lane] = oA[ht][3];
            PubB[2][ht * 4 + 0][lane] = oB[ht][0];
            PubB[2][ht * 4 + 1][lane] = oB[ht][1];
            PubB[2][ht * 4 + 2][lane] = oB[ht][2];
            PubB[2][ht * 4 + 3][lane] = oB[ht][3];
        }
        LA[2][lane] = lsA;
        LB[2][lane] = lsB;
    }
    __syncthreads();

    if (wave < 2) {
        f32x4 mo[4];
        float mls;
        if (wave == 0) {
            mo[0] = oA[0]; mo[1] = oA[1]; mo[2] = oA[2]; mo[3] = oA[3];
            mls = lsA;
        } else {
            mo[0] = oB[0]; mo[1] = oB[1]; mo[2] = oB[2]; mo[3] = oB[3];
            mls = lsB;
        }
        const float (*P)[16][64] = (wave == 0) ? PubA : PubB;
        const float (*L)[64]     = (wave == 0) ? LA : LB;
#pragma unroll
        for (int j = 0; j < 3; ++j) {
#pragma unroll
            for (int ht = 0; ht < 4; ++ht) {
                mo[ht][0] += P[j][ht * 4 + 0][lane];
                mo[ht][1] += P[j][ht * 4 + 1][lane];
                mo[ht][2] += P[j][ht * 4 + 2][lane];
                mo[ht][3] += P[j][ht * 4 + 3][lane];
            }
            mls += L[j][lane];
        }

        mls += __shfl_xor(mls, 16, 64);
        mls += __shfl_xor(mls, 32, 64);
        float inv = 1.0f / mls;

        float* orow = out + ((size_t)b * Tseq + qbase + wave * 16 + m) * 64;
        float4 wv;
#pragma unroll
        for (int ht = 0; ht < 4; ++ht) {
            wv.x = mo[ht][0] * inv; wv.y = mo[ht][1] * inv;
            wv.z = mo[ht][2] * inv; wv.w = mo[ht][3] * inv;
            *(float4a*)(orow + ht * 16 + quad * 4) = wv;
        }
    }
}

extern "C" void kernel_launch(void* const* d_in, const int* in_sizes, int n_in,
                              void* d_out, int out_size, void* d_ws, size_t ws_size,
                              hipStream_t stream) {
    const float* x  = (const float*)d_in[0];
    const float* Wq = (const float*)d_in[1];
    const float* Wk = (const float*)d_in[2];
    const float* Wv = (const float*)d_in[3];
    float* out = (float*)d_out;

    char* ws = (char*)d_ws;
    u16* wtf = (u16*)ws;                                       // 384 KiB
    u16* qb  = (u16*)(ws + 512 * 1024);                        // 4 MiB
    u16* kA  = (u16*)(ws + 512 * 1024 + 4 * 1024 * 1024);      // 4 MiB
    u16* vA  = (u16*)(ws + 512 * 1024 + 8 * 1024 * 1024);      // 4 MiB

    wt_kernel<<<96, 256, 0, stream>>>(Wq, Wk, Wv, wtf);
    proj_kernel<<<512, 256, 0, stream>>>(x, wtf, qb, kA, vA);
    attn_kernel<<<1024, 256, 0, stream>>>(qb, kA, vA, out);
}

// Round 7
// 242.690 us; speedup vs baseline: 1.0312x; 1.0312x over previous
//
#include <hip/hip_runtime.h>
#include <hip/hip_bf16.h>

typedef __attribute__((ext_vector_type(8))) short short8;
typedef __attribute__((ext_vector_type(4))) float f32x4;
typedef unsigned short u16;
typedef unsigned int u32;
typedef unsigned long long u64;

typedef u64    __attribute__((may_alias)) u64a;
typedef short8 __attribute__((may_alias)) short8a;
typedef float4 __attribute__((may_alias)) float4a;

#define Tseq 4096
#define LPP  72

__device__ __forceinline__ u32 pk_bf(float a, float b) {
    union { __hip_bfloat162 h; u32 u; } t;
    float2 f; f.x = a; f.y = b;
    t.h = __float22bfloat162_rn(f);
    return t.u;
}

__device__ __forceinline__ u16 f2bf(float f) {
    u32 u = __float_as_uint(f);
    u = (u + 0x7FFFu + ((u >> 16) & 1u)) >> 16;
    return (u16)u;
}

__device__ __forceinline__ short8 ld_frag_lds(const u16* p) {
    union { short8 v; u64 u[2]; } t;
    t.u[0] = *(const u64a*)(p);
    t.u[1] = *(const u64a*)(p + 4);
    return t.v;
}

__device__ __forceinline__ short8 cvt8(float4 a, float4 b) {
    union { short8 s; u32 u[4]; } t;
    t.u[0] = pk_bf(a.x, a.y); t.u[1] = pk_bf(a.z, a.w);
    t.u[2] = pk_bf(b.x, b.y); t.u[3] = pk_bf(b.z, b.w);
    return t.s;
}

__device__ __forceinline__ void gld_lds16(const void* g, void* l) {
    __builtin_amdgcn_global_load_lds(
        (const __attribute__((address_space(1))) u32*)g,
        (__attribute__((address_space(3))) u32*)l, 16, 0, 0);
}

// ---- W -> fragment-major bf16 (B-operand layout), 1/sqrt(C) folded into Wq ----
__global__ __launch_bounds__(256) void wt_kernel(const float* __restrict__ Wq,
                                                 const float* __restrict__ Wk,
                                                 const float* __restrict__ Wv,
                                                 u16* __restrict__ wtf) {
    int idx = blockIdx.x * 256 + threadIdx.x;
    int lane = idx & 63, cc = (idx >> 6) & 31, n = (idx >> 11) & 3, mat = idx >> 13;
    const float* W = (mat == 0) ? Wq : ((mat == 1) ? Wk : Wv);
    float sc = (mat == 0) ? 0.03125f : 1.0f;
    int h = n * 16 + (lane & 15);
    int cbase = cc * 32 + (lane >> 4) * 8;
    union { short8 s; u32 u[4]; } t;
#pragma unroll
    for (int j2 = 0; j2 < 4; ++j2) {
        float a = W[(size_t)(cbase + j2 * 2)     * 64 + h] * sc;
        float b = W[(size_t)(cbase + j2 * 2 + 1) * 64 + h] * sc;
        t.u[j2] = pk_bf(a, b);
    }
    *(short8a*)(wtf + (size_t)idx * 8) = t.s;
}

// ---- QKV projection: async-LDS W staging (double-buffered), x reg pipeline ----
__global__ __launch_bounds__(256, 2) void proj_kernel(const float* __restrict__ x,
                                                      const u16* __restrict__ wtf,
                                                      u16* __restrict__ qb,
                                                      u16* __restrict__ kA,
                                                      u16* __restrict__ vA) {
    // phase = 2 cc's; buf = 12 mn x 2 ccp x 64 lanes x 8 u16 = 24 KiB
    __shared__ __align__(16) u16 Wl[2][12 * 2 * 64 * 8];

    const int tid = threadIdx.x, lane = tid & 63, wave = tid >> 6;
    const int m = lane & 15, quad = lane >> 4;
    const long rowbase = (long)blockIdx.x * 64 + wave * 16;
    const float* xr = x + (rowbase + m) * 1024 + quad * 8;

    f32x4 acc[12];
#pragma unroll
    for (int i = 0; i < 12; ++i) acc[i] = (f32x4){0.f, 0.f, 0.f, 0.f};

    // stage phase p into Wl[buf]: 24 chunks of 1 KiB; this wave does 6
#define STAGE(p, buf)                                                          \
    {                                                                          \
        _Pragma("unroll")                                                      \
        for (int i = 0; i < 6; ++i) {                                          \
            int c = wave * 6 + i, mn = c >> 1, ccp = c & 1;                    \
            const u16* g = wtf + ((size_t)(mn * 32 + (p) * 2 + ccp) * 64 + lane) * 8; \
            u16* l = &Wl[buf][(size_t)(mn * 2 + ccp) * 512];                   \
            gld_lds16(g, l);                                                   \
        }                                                                      \
    }

    float4 xa[4], xb[4];
#pragma unroll
    for (int t = 0; t < 4; ++t)
        xa[t] = *(const float4a*)(xr + (t >> 1) * 32 + (t & 1) * 4);
#pragma unroll
    for (int t = 0; t < 4; ++t)
        xb[t] = *(const float4a*)(xr + (2 + (t >> 1)) * 32 + (t & 1) * 4);

    STAGE(0, 0);
    __syncthreads();

    for (int p = 0; p < 16; ++p) {
        if (p < 15) STAGE(p + 1, (p + 1) & 1);
        float4 xn[4];
        if (p < 14) {
#pragma unroll
            for (int t = 0; t < 4; ++t)
                xn[t] = *(const float4a*)(xr + (2 * (p + 2) + (t >> 1)) * 32 + (t & 1) * 4);
        }
        const u16* wb = Wl[p & 1];
#pragma unroll
        for (int ccp = 0; ccp < 2; ++ccp) {
            short8 af = cvt8(xa[ccp * 2], xa[ccp * 2 + 1]);
#pragma unroll
            for (int mn = 0; mn < 12; ++mn) {
                short8 bf = *(const short8a*)(wb + ((size_t)(mn * 2 + ccp) * 64 + lane) * 8);
                acc[mn] = __builtin_amdgcn_mfma_f32_16x16x32_bf16(af, bf, acc[mn], 0, 0, 0);
            }
        }
#pragma unroll
        for (int t = 0; t < 4; ++t) { xa[t] = xb[t]; if (p < 14) xb[t] = xn[t]; }
        __syncthreads();
    }
#undef STAGE

    const int b  = (int)(rowbase >> 12);
    const int tb = (int)(rowbase & 4095);

    // q: natural [t][h]
#pragma unroll
    for (int n = 0; n < 4; ++n)
#pragma unroll
        for (int r = 0; r < 4; ++r)
            qb[(rowbase + quad * 4 + r) * 64 + n * 16 + m] = f2bf(acc[n][r]);

    // kA[b][key>>4][h>>5][(key&15)+16*((h>>3)&3)][h&7]
#pragma unroll
    for (int n = 0; n < 4; ++n) {
        int kk = n >> 1;
        int lq = (n * 2 + (m >> 3)) & 3;
        int j  = m & 7;
#pragma unroll
        for (int r = 0; r < 4; ++r) {
            int key = tb + quad * 4 + r;
            size_t a = ((((size_t)b * 256 + (key >> 4)) * 2 + kk) * 64
                        + ((key & 15) + 16 * lq)) * 8 + j;
            kA[a] = f2bf(acc[4 + n][r]);
        }
    }

    // vA[b][h>>4][key>>5][(h&15)+16*((key>>3)&3)][key&7]
    {
        int key0 = tb + quad * 4;
        int j0 = key0 & 7;
        int q2 = (key0 >> 3) & 3;
        int kc = key0 >> 5;
#pragma unroll
        for (int n = 0; n < 4; ++n) {
            u64 pv = (u64)pk_bf(acc[8 + n][0], acc[8 + n][1])
                   | ((u64)pk_bf(acc[8 + n][2], acc[8 + n][3]) << 32);
            size_t a = ((((size_t)b * 4 + n) * 128 + kc) * 64 + (m + 16 * q2)) * 8 + j0;
            *(u64a*)(vA + a) = pv;
        }
    }
}

// ---- attention: 64-row blocks = 2 row-groups x 2 K-halves; paired-wave L1 reuse ----
// Waves (0,1) both walk kt in [0,mid); waves (2,3) walk [mid,T). Each pair's
// address stream is IDENTICAL (addresses depend on lane/kt only, not row-group)
// and started together -> the pair's 16 KB/step is fetched from L2 once and
// L1-served for the second reader: ~2x effective L2-traffic cut with zero
// barriers and zero extra registers. Inner loop byte-identical to R5.
// 512 blocks <= 2/CU -> ALL blocks resident at t=0 (no mapping assumptions);
// heavy-first (LPT) order. Merge: one publisher (hf=1) per row-group.
struct K8 { short8 k[8]; };

__device__ __forceinline__ void loadK(K8& f, const u16* kAb, int kt, int lane) {
    const u16* kp = kAb + (size_t)kt * 4096 + (size_t)lane * 8;
#pragma unroll
    for (int mt = 0; mt < 4; ++mt) {
        f.k[mt * 2]     = *(const short8a*)(kp + mt * 1024);
        f.k[mt * 2 + 1] = *(const short8a*)(kp + mt * 1024 + 512);
    }
}

__device__ __forceinline__ void loadV(short8* vf, const u16* vAb, int kt, int lane) {
    const u16* vp = vAb + (size_t)kt * 1024 + (size_t)lane * 8;
#pragma unroll
    for (int ht = 0; ht < 4; ++ht) {
        vf[ht * 2]     = *(const short8a*)(vp + (size_t)ht * 65536);
        vf[ht * 2 + 1] = *(const short8a*)(vp + (size_t)ht * 65536 + 512);
    }
}

// QK^T + mask + fixed-max softmax + P -> LDS for one 16-row substrip
__device__ __forceinline__ void qk_sm(const K8& f, short8 qf0, short8 qf1,
        u16* pw, float& lsum, int kt, int n_s, int qrow, int quad, int m) {
    const float L2E = 1.4426950408889634f;
    const float FMB = 4.0f * L2E;
    f32x4 s[4];
    __builtin_amdgcn_s_setprio(1);
#pragma unroll
    for (int mt = 0; mt < 4; ++mt) {
        f32x4 a = (f32x4){0.f, 0.f, 0.f, 0.f};
        a = __builtin_amdgcn_mfma_f32_16x16x32_bf16(f.k[mt * 2],     qf0, a, 0, 0, 0);
        a = __builtin_amdgcn_mfma_f32_16x16x32_bf16(f.k[mt * 2 + 1], qf1, a, 0, 0, 0);
        s[mt] = a;
    }
    __builtin_amdgcn_s_setprio(0);
    if (kt == n_s) {
#pragma unroll
        for (int mt = 0; mt < 4; ++mt)
#pragma unroll
            for (int r = 0; r < 4; ++r) {
                int key = kt * 64 + mt * 16 + quad * 4 + r;
                if (key > qrow) s[mt][r] = -1e30f;
            }
    }
#pragma unroll
    for (int mt = 0; mt < 4; ++mt) {
        float p0 = __builtin_amdgcn_exp2f(s[mt][0] * L2E - FMB);
        float p1 = __builtin_amdgcn_exp2f(s[mt][1] * L2E - FMB);
        float p2 = __builtin_amdgcn_exp2f(s[mt][2] * L2E - FMB);
        float p3 = __builtin_amdgcn_exp2f(s[mt][3] * L2E - FMB);
        lsum += (p0 + p1) + (p2 + p3);
        u64 pv = (u64)pk_bf(p0, p1) | ((u64)pk_bf(p2, p3) << 32);
        *(u64a*)(pw + m * LPP + mt * 16 + quad * 4) = pv;
    }
}

__global__ __launch_bounds__(256, 2) void attn_kernel(const u16* __restrict__ qb,
                                                      const u16* __restrict__ kA,
                                                      const u16* __restrict__ vA,
                                                      float* __restrict__ out) {
    __shared__ __align__(16) u16 Pt[4][2][16 * LPP];   // 18 KiB
    __shared__ float PubA[2][16][64];                  // 8 KiB
    __shared__ float PubB[2][16][64];                  // 8 KiB
    __shared__ float LA[2][64], LB[2][64];             // 1 KiB

    const int tid = threadIdx.x, lane = tid & 63, wave = tid >> 6;
    const int m = lane & 15, quad = lane >> 4;
    const int beta = blockIdx.x;
    const int b = beta & 7;                 // XCD affinity: one batch per XCD
    const int u = beta >> 3;                // 0..63
    const int g = 63 - u;                   // heavy strips dispatch first (LPT)
    const int n_s = g;                      // diagonal 64-key tile
    const int T = g + 1;
    const int qbase = g * 64;

    const int rg = wave & 1;                // row-group (rows qbase + rg*32 ..)
    const int hf = wave >> 1;               // K-half
    const int mid = (T + 1) >> 1;
    const int kt0 = hf ? mid : 0;
    const int kt1 = hf ? (T - 1) : (mid - 1);   // inclusive

    const u16* qpA = qb + ((size_t)b * Tseq + qbase + rg * 32 + m) * 64;
    const u16* qpB = qpA + 16 * 64;
    short8 qA0 = *(const short8a*)(qpA + quad * 8);
    short8 qA1 = *(const short8a*)(qpA + 32 + quad * 8);
    short8 qB0 = *(const short8a*)(qpB + quad * 8);
    short8 qB1 = *(const short8a*)(qpB + 32 + quad * 8);

    const u16* kAb = kA + (size_t)b * (256 * 2 * 64 * 8);
    const u16* vAb = vA + (size_t)b * (4 * 128 * 64 * 8);
    u16* pwA = Pt[wave][0];
    u16* pwB = Pt[wave][1];

    f32x4 oA[4], oB[4];
#pragma unroll
    for (int ht = 0; ht < 4; ++ht) {
        oA[ht] = (f32x4){0.f, 0.f, 0.f, 0.f};
        oB[ht] = (f32x4){0.f, 0.f, 0.f, 0.f};
    }
    float lsA = 0.f, lsB = 0.f;
    const int qrowA = qbase + rg * 32 + m;
    const int qrowB = qrowA + 16;

    if (kt0 <= kt1) {
        K8 ka;
        short8 vf[8];
        loadK(ka, kAb, kt0, lane);
        for (int kt = kt0;; ++kt) {
            loadV(vf, vAb, kt, lane);        // early: consumed after 2 softmaxes
            qk_sm(ka, qA0, qA1, pwA, lsA, kt, n_s, qrowA, quad, m);
            qk_sm(ka, qB0, qB1, pwB, lsB, kt, n_s, qrowB, quad, m);
            if (kt < kt1) loadK(ka, kAb, kt + 1, lane);  // after last ka read
            __builtin_amdgcn_wave_barrier();
            short8 pA0 = ld_frag_lds(pwA + m * LPP + quad * 8);
            short8 pA1 = ld_frag_lds(pwA + m * LPP + 32 + quad * 8);
            short8 pB0 = ld_frag_lds(pwB + m * LPP + quad * 8);
            short8 pB1 = ld_frag_lds(pwB + m * LPP + 32 + quad * 8);
            __builtin_amdgcn_s_setprio(1);
            oA[0] = __builtin_amdgcn_mfma_f32_16x16x32_bf16(vf[0], pA0, oA[0], 0, 0, 0);
            oA[0] = __builtin_amdgcn_mfma_f32_16x16x32_bf16(vf[1], pA1, oA[0], 0, 0, 0);
            oA[1] = __builtin_amdgcn_mfma_f32_16x16x32_bf16(vf[2], pA0, oA[1], 0, 0, 0);
            oA[1] = __builtin_amdgcn_mfma_f32_16x16x32_bf16(vf[3], pA1, oA[1], 0, 0, 0);
            oA[2] = __builtin_amdgcn_mfma_f32_16x16x32_bf16(vf[4], pA0, oA[2], 0, 0, 0);
            oA[2] = __builtin_amdgcn_mfma_f32_16x16x32_bf16(vf[5], pA1, oA[2], 0, 0, 0);
            oA[3] = __builtin_amdgcn_mfma_f32_16x16x32_bf16(vf[6], pA0, oA[3], 0, 0, 0);
            oA[3] = __builtin_amdgcn_mfma_f32_16x16x32_bf16(vf[7], pA1, oA[3], 0, 0, 0);
            oB[0] = __builtin_amdgcn_mfma_f32_16x16x32_bf16(vf[0], pB0, oB[0], 0, 0, 0);
            oB[0] = __builtin_amdgcn_mfma_f32_16x16x32_bf16(vf[1], pB1, oB[0], 0, 0, 0);
            oB[1] = __builtin_amdgcn_mfma_f32_16x16x32_bf16(vf[2], pB0, oB[1], 0, 0, 0);
            oB[1] = __builtin_amdgcn_mfma_f32_16x16x32_bf16(vf[3], pB1, oB[1], 0, 0, 0);
            oB[2] = __builtin_amdgcn_mfma_f32_16x16x32_bf16(vf[4], pB0, oB[2], 0, 0, 0);
            oB[2] = __builtin_amdgcn_mfma_f32_16x16x32_bf16(vf[5], pB1, oB[2], 0, 0, 0);
            oB[3] = __builtin_amdgcn_mfma_f32_16x16x32_bf16(vf[6], pB0, oB[3], 0, 0, 0);
            oB[3] = __builtin_amdgcn_mfma_f32_16x16x32_bf16(vf[7], pB1, oB[3], 0, 0, 0);
            __builtin_amdgcn_s_setprio(0);
            if (kt == kt1) break;
        }
    }

    // merge halves per row-group: hf=1 publishes, hf=0 accumulates+finalizes.
    if (hf == 1) {
#pragma unroll
        for (int ht = 0; ht < 4; ++ht) {
            PubA[rg][ht * 4 + 0][lane] = oA[ht][0];
            PubA[rg][ht * 4 + 1][lane] = oA[ht][1];
            PubA[rg][ht * 4 + 2][lane] = oA[ht][2];
            PubA[rg][ht * 4 + 3][lane] = oA[ht][3];
            PubB[rg][ht * 4 + 0][lane] = oB[ht][0];
            PubB[rg][ht * 4 + 1][lane] = oB[ht][1];
            PubB[rg][ht * 4 + 2][lane] = oB[ht][2];
            PubB[rg][ht * 4 + 3][lane] = oB[ht][3];
        }
        LA[rg][lane] = lsA;
        LB[rg][lane] = lsB;
    }
    __syncthreads();
    if (hf == 0) {
#pragma unroll
        for (int ht = 0; ht < 4; ++ht) {
            oA[ht][0] += PubA[rg][ht * 4 + 0][lane];
            oA[ht][1] += PubA[rg][ht * 4 + 1][lane];
            oA[ht][2] += PubA[rg][ht * 4 + 2][lane];
            oA[ht][3] += PubA[rg][ht * 4 + 3][lane];
            oB[ht][0] += PubB[rg][ht * 4 + 0][lane];
            oB[ht][1] += PubB[rg][ht * 4 + 1][lane];
            oB[ht][2] += PubB[rg][ht * 4 + 2][lane];
            oB[ht][3] += PubB[rg][ht * 4 + 3][lane];
        }
        lsA += LA[rg][lane];
        lsB += LB[rg][lane];

        lsA += __shfl_xor(lsA, 16, 64);
        lsA += __shfl_xor(lsA, 32, 64);
        lsB += __shfl_xor(lsB, 16, 64);
        lsB += __shfl_xor(lsB, 32, 64);
        float invA = 1.0f / lsA;
        float invB = 1.0f / lsB;

        float* orowA = out + ((size_t)b * Tseq + qbase + rg * 32 + m) * 64;
        float* orowB = orowA + 16 * 64;
        float4 wv;
#pragma unroll
        for (int ht = 0; ht < 4; ++ht) {
            wv.x = oA[ht][0] * invA; wv.y = oA[ht][1] * invA;
            wv.z = oA[ht][2] * invA; wv.w = oA[ht][3] * invA;
            *(float4a*)(orowA + ht * 16 + quad * 4) = wv;
        }
#pragma unroll
        for (int ht = 0; ht < 4; ++ht) {
            wv.x = oB[ht][0] * invB; wv.y = oB[ht][1] * invB;
            wv.z = oB[ht][2] * invB; wv.w = oB[ht][3] * invB;
            *(float4a*)(orowB + ht * 16 + quad * 4) = wv;
        }
    }
}

extern "C" void kernel_launch(void* const* d_in, const int* in_sizes, int n_in,
                              void* d_out, int out_size, void* d_ws, size_t ws_size,
                              hipStream_t stream) {
    const float* x  = (const float*)d_in[0];
    const float* Wq = (const float*)d_in[1];
    const float* Wk = (const float*)d_in[2];
    const float* Wv = (const float*)d_in[3];
    float* out = (float*)d_out;

    char* ws = (char*)d_ws;
    u16* wtf = (u16*)ws;                                       // 384 KiB
    u16* qb  = (u16*)(ws + 512 * 1024);                        // 4 MiB
    u16* kA  = (u16*)(ws + 512 * 1024 + 4 * 1024 * 1024);      // 4 MiB
    u16* vA  = (u16*)(ws + 512 * 1024 + 8 * 1024 * 1024);      // 4 MiB

    wt_kernel<<<96, 256, 0, stream>>>(Wq, Wk, Wv, wtf);
    proj_kernel<<<512, 256, 0, stream>>>(x, wtf, qb, kA, vA);
    attn_kernel<<<512, 256, 0, stream>>>(qb, kA, vA, out);
}

// Round 8
// 234.327 us; speedup vs baseline: 1.0680x; 1.0357x over previous
//
#include <hip/hip_runtime.h>
#include <hip/hip_bf16.h>

typedef __attribute__((ext_vector_type(8))) short short8;
typedef __attribute__((ext_vector_type(4))) float f32x4;
typedef unsigned short u16;
typedef unsigned int u32;
typedef unsigned long long u64;

typedef u64    __attribute__((may_alias)) u64a;
typedef short8 __attribute__((may_alias)) short8a;
typedef float4 __attribute__((may_alias)) float4a;

#define Tseq 4096
#define LPP  72

__device__ __forceinline__ u32 pk_bf(float a, float b) {
    union { __hip_bfloat162 h; u32 u; } t;
    float2 f; f.x = a; f.y = b;
    t.h = __float22bfloat162_rn(f);
    return t.u;
}

__device__ __forceinline__ u16 f2bf(float f) {
    u32 u = __float_as_uint(f);
    u = (u + 0x7FFFu + ((u >> 16) & 1u)) >> 16;
    return (u16)u;
}

__device__ __forceinline__ short8 ld_frag_lds(const u16* p) {
    union { short8 v; u64 u[2]; } t;
    t.u[0] = *(const u64a*)(p);
    t.u[1] = *(const u64a*)(p + 4);
    return t.v;
}

__device__ __forceinline__ short8 cvt8(float4 a, float4 b) {
    union { short8 s; u32 u[4]; } t;
    t.u[0] = pk_bf(a.x, a.y); t.u[1] = pk_bf(a.z, a.w);
    t.u[2] = pk_bf(b.x, b.y); t.u[3] = pk_bf(b.z, b.w);
    return t.s;
}

__device__ __forceinline__ void gld_lds16(const void* g, void* l) {
    __builtin_amdgcn_global_load_lds(
        (const __attribute__((address_space(1))) u32*)g,
        (__attribute__((address_space(3))) u32*)l, 16, 0, 0);
}

// ---- W -> fragment-major bf16 (B-operand layout), 1/sqrt(C) folded into Wq ----
__global__ __launch_bounds__(256) void wt_kernel(const float* __restrict__ Wq,
                                                 const float* __restrict__ Wk,
                                                 const float* __restrict__ Wv,
                                                 u16* __restrict__ wtf) {
    int idx = blockIdx.x * 256 + threadIdx.x;
    int lane = idx & 63, cc = (idx >> 6) & 31, n = (idx >> 11) & 3, mat = idx >> 13;
    const float* W = (mat == 0) ? Wq : ((mat == 1) ? Wk : Wv);
    float sc = (mat == 0) ? 0.03125f : 1.0f;
    int h = n * 16 + (lane & 15);
    int cbase = cc * 32 + (lane >> 4) * 8;
    union { short8 s; u32 u[4]; } t;
#pragma unroll
    for (int j2 = 0; j2 < 4; ++j2) {
        float a = W[(size_t)(cbase + j2 * 2)     * 64 + h] * sc;
        float b = W[(size_t)(cbase + j2 * 2 + 1) * 64 + h] * sc;
        t.u[j2] = pk_bf(a, b);
    }
    *(short8a*)(wtf + (size_t)idx * 8) = t.s;
}

// ---- QKV projection: async-LDS W staging (double-buffered), x reg pipeline ----
__global__ __launch_bounds__(256, 2) void proj_kernel(const float* __restrict__ x,
                                                      const u16* __restrict__ wtf,
                                                      u16* __restrict__ qb,
                                                      u16* __restrict__ kA,
                                                      u16* __restrict__ vA) {
    // phase = 2 cc's; buf = 12 mn x 2 ccp x 64 lanes x 8 u16 = 24 KiB
    __shared__ __align__(16) u16 Wl[2][12 * 2 * 64 * 8];

    const int tid = threadIdx.x, lane = tid & 63, wave = tid >> 6;
    const int m = lane & 15, quad = lane >> 4;
    const long rowbase = (long)blockIdx.x * 64 + wave * 16;
    const float* xr = x + (rowbase + m) * 1024 + quad * 8;

    f32x4 acc[12];
#pragma unroll
    for (int i = 0; i < 12; ++i) acc[i] = (f32x4){0.f, 0.f, 0.f, 0.f};

    // stage phase p into Wl[buf]: 24 chunks of 1 KiB; this wave does 6
#define STAGE(p, buf)                                                          \
    {                                                                          \
        _Pragma("unroll")                                                      \
        for (int i = 0; i < 6; ++i) {                                          \
            int c = wave * 6 + i, mn = c >> 1, ccp = c & 1;                    \
            const u16* g = wtf + ((size_t)(mn * 32 + (p) * 2 + ccp) * 64 + lane) * 8; \
            u16* l = &Wl[buf][(size_t)(mn * 2 + ccp) * 512];                   \
            gld_lds16(g, l);                                                   \
        }                                                                      \
    }

    float4 xa[4], xb[4];
#pragma unroll
    for (int t = 0; t < 4; ++t)
        xa[t] = *(const float4a*)(xr + (t >> 1) * 32 + (t & 1) * 4);
#pragma unroll
    for (int t = 0; t < 4; ++t)
        xb[t] = *(const float4a*)(xr + (2 + (t >> 1)) * 32 + (t & 1) * 4);

    STAGE(0, 0);
    __syncthreads();

    for (int p = 0; p < 16; ++p) {
        if (p < 15) STAGE(p + 1, (p + 1) & 1);
        float4 xn[4];
        if (p < 14) {
#pragma unroll
            for (int t = 0; t < 4; ++t)
                xn[t] = *(const float4a*)(xr + (2 * (p + 2) + (t >> 1)) * 32 + (t & 1) * 4);
        }
        const u16* wb = Wl[p & 1];
#pragma unroll
        for (int ccp = 0; ccp < 2; ++ccp) {
            short8 af = cvt8(xa[ccp * 2], xa[ccp * 2 + 1]);
#pragma unroll
            for (int mn = 0; mn < 12; ++mn) {
                short8 bf = *(const short8a*)(wb + ((size_t)(mn * 2 + ccp) * 64 + lane) * 8);
                acc[mn] = __builtin_amdgcn_mfma_f32_16x16x32_bf16(af, bf, acc[mn], 0, 0, 0);
            }
        }
#pragma unroll
        for (int t = 0; t < 4; ++t) { xa[t] = xb[t]; if (p < 14) xb[t] = xn[t]; }
        __syncthreads();
    }
#undef STAGE

    const int b  = (int)(rowbase >> 12);
    const int tb = (int)(rowbase & 4095);

    // q: natural [t][h]
#pragma unroll
    for (int n = 0; n < 4; ++n)
#pragma unroll
        for (int r = 0; r < 4; ++r)
            qb[(rowbase + quad * 4 + r) * 64 + n * 16 + m] = f2bf(acc[n][r]);

    // kA[b][key>>4][h>>5][(key&15)+16*((h>>3)&3)][h&7]
#pragma unroll
    for (int n = 0; n < 4; ++n) {
        int kk = n >> 1;
        int lq = (n * 2 + (m >> 3)) & 3;
        int j  = m & 7;
#pragma unroll
        for (int r = 0; r < 4; ++r) {
            int key = tb + quad * 4 + r;
            size_t a = ((((size_t)b * 256 + (key >> 4)) * 2 + kk) * 64
                        + ((key & 15) + 16 * lq)) * 8 + j;
            kA[a] = f2bf(acc[4 + n][r]);
        }
    }

    // vA[b][h>>4][key>>5][(h&15)+16*((key>>3)&3)][key&7]
    {
        int key0 = tb + quad * 4;
        int j0 = key0 & 7;
        int q2 = (key0 >> 3) & 3;
        int kc = key0 >> 5;
#pragma unroll
        for (int n = 0; n < 4; ++n) {
            u64 pv = (u64)pk_bf(acc[8 + n][0], acc[8 + n][1])
                   | ((u64)pk_bf(acc[8 + n][2], acc[8 + n][3]) << 32);
            size_t a = ((((size_t)b * 4 + n) * 128 + kc) * 64 + (m + 16 * q2)) * 8 + j0;
            *(u64a*)(vA + a) = pv;
        }
    }
}

// ---- attention: one 32-row strip per block, 4-way split-K, 3 blocks/CU ----
// Best verified configuration (session R5). 32 rows/wave = verified AI sweet
// spot (64 spills, 16 doubles L2 traffic). Single K buffer + early V. Waves
// barrier-free in the K-loop; split-K parts differ by <=1 tile. Fixed-max
// softmax makes the end-merge pure adds. Serpentine LPT strip mapping.
struct K8 { short8 k[8]; };

__device__ __forceinline__ void loadK(K8& f, const u16* kAb, int kt, int lane) {
    const u16* kp = kAb + (size_t)kt * 4096 + (size_t)lane * 8;
#pragma unroll
    for (int mt = 0; mt < 4; ++mt) {
        f.k[mt * 2]     = *(const short8a*)(kp + mt * 1024);
        f.k[mt * 2 + 1] = *(const short8a*)(kp + mt * 1024 + 512);
    }
}

__device__ __forceinline__ void loadV(short8* vf, const u16* vAb, int kt, int lane) {
    const u16* vp = vAb + (size_t)kt * 1024 + (size_t)lane * 8;
#pragma unroll
    for (int ht = 0; ht < 4; ++ht) {
        vf[ht * 2]     = *(const short8a*)(vp + (size_t)ht * 65536);
        vf[ht * 2 + 1] = *(const short8a*)(vp + (size_t)ht * 65536 + 512);
    }
}

// QK^T + mask + fixed-max softmax + P -> LDS for one 16-row substrip
__device__ __forceinline__ void qk_sm(const K8& f, short8 qf0, short8 qf1,
        u16* pw, float& lsum, int kt, int n_s, int qrow, int quad, int m) {
    const float L2E = 1.4426950408889634f;
    const float FMB = 4.0f * L2E;
    f32x4 s[4];
    __builtin_amdgcn_s_setprio(1);
#pragma unroll
    for (int mt = 0; mt < 4; ++mt) {
        f32x4 a = (f32x4){0.f, 0.f, 0.f, 0.f};
        a = __builtin_amdgcn_mfma_f32_16x16x32_bf16(f.k[mt * 2],     qf0, a, 0, 0, 0);
        a = __builtin_amdgcn_mfma_f32_16x16x32_bf16(f.k[mt * 2 + 1], qf1, a, 0, 0, 0);
        s[mt] = a;
    }
    __builtin_amdgcn_s_setprio(0);
    if (kt == n_s) {
#pragma unroll
        for (int mt = 0; mt < 4; ++mt)
#pragma unroll
            for (int r = 0; r < 4; ++r) {
                int key = kt * 64 + mt * 16 + quad * 4 + r;
                if (key > qrow) s[mt][r] = -1e30f;
            }
    }
#pragma unroll
    for (int mt = 0; mt < 4; ++mt) {
        float p0 = __builtin_amdgcn_exp2f(s[mt][0] * L2E - FMB);
        float p1 = __builtin_amdgcn_exp2f(s[mt][1] * L2E - FMB);
        float p2 = __builtin_amdgcn_exp2f(s[mt][2] * L2E - FMB);
        float p3 = __builtin_amdgcn_exp2f(s[mt][3] * L2E - FMB);
        lsum += (p0 + p1) + (p2 + p3);
        u64 pv = (u64)pk_bf(p0, p1) | ((u64)pk_bf(p2, p3) << 32);
        *(u64a*)(pw + m * LPP + mt * 16 + quad * 4) = pv;
    }
}

__global__ __launch_bounds__(256, 3) void attn_kernel(const u16* __restrict__ qb,
                                                      const u16* __restrict__ kA,
                                                      const u16* __restrict__ vA,
                                                      float* __restrict__ out) {
    __shared__ __align__(16) u16 Pt[4][2][16 * LPP];   // 18 KiB
    __shared__ float PubA[3][16][64];                  // 12 KiB
    __shared__ float PubB[3][16][64];                  // 12 KiB
    __shared__ float LA[3][64], LB[3][64];             // 1.5 KiB

    const int tid = threadIdx.x, lane = tid & 63, wave = tid >> 6;
    const int m = lane & 15, quad = lane >> 4;
    const int beta = blockIdx.x;
    const int b = beta & 7;                 // XCD affinity: one batch per XCD
    const int u = beta >> 3;                // 0..127 within XCD
    // serpentine rank: CU c gets ranks c, 63-c, 64+c, 127-c (sum 130/132)
    const int kseg = u >> 5, c = u & 31;
    const int rho = (kseg & 1) ? (kseg * 32 + 31 - c) : (kseg * 32 + c);
    const int n_s = 63 - (rho >> 1);        // diagonal 64-key tile
    const int T = n_s + 1;
    const int g = n_s * 2 + (rho & 1);      // 32-row strip index, 0..127
    const int qbase = g * 32;

    // split-K: wave = part; contiguous, lengths differ by <=1
    const int kt0 = wave * T / 4;
    const int kt1 = (wave + 1) * T / 4 - 1; // inclusive; only wave 3 hits n_s

    const u16* qpA = qb + ((size_t)b * Tseq + qbase + m) * 64;
    const u16* qpB = qpA + 16 * 64;
    short8 qA0 = *(const short8a*)(qpA + quad * 8);
    short8 qA1 = *(const short8a*)(qpA + 32 + quad * 8);
    short8 qB0 = *(const short8a*)(qpB + quad * 8);
    short8 qB1 = *(const short8a*)(qpB + 32 + quad * 8);

    const u16* kAb = kA + (size_t)b * (256 * 2 * 64 * 8);
    const u16* vAb = vA + (size_t)b * (4 * 128 * 64 * 8);
    u16* pwA = Pt[wave][0];
    u16* pwB = Pt[wave][1];

    f32x4 oA[4], oB[4];
#pragma unroll
    for (int ht = 0; ht < 4; ++ht) {
        oA[ht] = (f32x4){0.f, 0.f, 0.f, 0.f};
        oB[ht] = (f32x4){0.f, 0.f, 0.f, 0.f};
    }
    float lsA = 0.f, lsB = 0.f;
    const int qrowA = qbase + m;
    const int qrowB = qbase + 16 + m;

    if (kt0 <= kt1) {
        K8 ka;
        short8 vf[8];
        loadK(ka, kAb, kt0, lane);
        for (int kt = kt0;; ++kt) {
            loadV(vf, vAb, kt, lane);        // early: consumed after 2 softmaxes
            qk_sm(ka, qA0, qA1, pwA, lsA, kt, n_s, qrowA, quad, m);
            qk_sm(ka, qB0, qB1, pwB, lsB, kt, n_s, qrowB, quad, m);
            if (kt < kt1) loadK(ka, kAb, kt + 1, lane);  // after last ka read
            __builtin_amdgcn_wave_barrier();
            short8 pA0 = ld_frag_lds(pwA + m * LPP + quad * 8);
            short8 pA1 = ld_frag_lds(pwA + m * LPP + 32 + quad * 8);
            short8 pB0 = ld_frag_lds(pwB + m * LPP + quad * 8);
            short8 pB1 = ld_frag_lds(pwB + m * LPP + 32 + quad * 8);
            __builtin_amdgcn_s_setprio(1);
            oA[0] = __builtin_amdgcn_mfma_f32_16x16x32_bf16(vf[0], pA0, oA[0], 0, 0, 0);
            oA[0] = __builtin_amdgcn_mfma_f32_16x16x32_bf16(vf[1], pA1, oA[0], 0, 0, 0);
            oA[1] = __builtin_amdgcn_mfma_f32_16x16x32_bf16(vf[2], pA0, oA[1], 0, 0, 0);
            oA[1] = __builtin_amdgcn_mfma_f32_16x16x32_bf16(vf[3], pA1, oA[1], 0, 0, 0);
            oA[2] = __builtin_amdgcn_mfma_f32_16x16x32_bf16(vf[4], pA0, oA[2], 0, 0, 0);
            oA[2] = __builtin_amdgcn_mfma_f32_16x16x32_bf16(vf[5], pA1, oA[2], 0, 0, 0);
            oA[3] = __builtin_amdgcn_mfma_f32_16x16x32_bf16(vf[6], pA0, oA[3], 0, 0, 0);
            oA[3] = __builtin_amdgcn_mfma_f32_16x16x32_bf16(vf[7], pA1, oA[3], 0, 0, 0);
            oB[0] = __builtin_amdgcn_mfma_f32_16x16x32_bf16(vf[0], pB0, oB[0], 0, 0, 0);
            oB[0] = __builtin_amdgcn_mfma_f32_16x16x32_bf16(vf[1], pB1, oB[0], 0, 0, 0);
            oB[1] = __builtin_amdgcn_mfma_f32_16x16x32_bf16(vf[2], pB0, oB[1], 0, 0, 0);
            oB[1] = __builtin_amdgcn_mfma_f32_16x16x32_bf16(vf[3], pB1, oB[1], 0, 0, 0);
            oB[2] = __builtin_amdgcn_mfma_f32_16x16x32_bf16(vf[4], pB0, oB[2], 0, 0, 0);
            oB[2] = __builtin_amdgcn_mfma_f32_16x16x32_bf16(vf[5], pB1, oB[2], 0, 0, 0);
            oB[3] = __builtin_amdgcn_mfma_f32_16x16x32_bf16(vf[6], pB0, oB[3], 0, 0, 0);
            oB[3] = __builtin_amdgcn_mfma_f32_16x16x32_bf16(vf[7], pB1, oB[3], 0, 0, 0);
            __builtin_amdgcn_s_setprio(0);
            if (kt == kt1) break;
        }
    }

    // merge: wave0 finalizes substrip A, wave1 substrip B; fixed-max softmax
    // makes partials pure adds. Publish slots: A from waves 1,2,3; B from 0,2,3.
    if (wave == 0) {
#pragma unroll
        for (int ht = 0; ht < 4; ++ht) {
            PubB[0][ht * 4 + 0][lane] = oB[ht][0];
            PubB[0][ht * 4 + 1][lane] = oB[ht][1];
            PubB[0][ht * 4 + 2][lane] = oB[ht][2];
            PubB[0][ht * 4 + 3][lane] = oB[ht][3];
        }
        LB[0][lane] = lsB;
    } else if (wave == 1) {
#pragma unroll
        for (int ht = 0; ht < 4; ++ht) {
            PubA[0][ht * 4 + 0][lane] = oA[ht][0];
            PubA[0][ht * 4 + 1][lane] = oA[ht][1];
            PubA[0][ht * 4 + 2][lane] = oA[ht][2];
            PubA[0][ht * 4 + 3][lane] = oA[ht][3];
        }
        LA[0][lane] = lsA;
    } else if (wave == 2) {
#pragma unroll
        for (int ht = 0; ht < 4; ++ht) {
            PubA[1][ht * 4 + 0][lane] = oA[ht][0];
            PubA[1][ht * 4 + 1][lane] = oA[ht][1];
            PubA[1][ht * 4 + 2][lane] = oA[ht][2];
            PubA[1][ht * 4 + 3][lane] = oA[ht][3];
            PubB[1][ht * 4 + 0][lane] = oB[ht][0];
            PubB[1][ht * 4 + 1][lane] = oB[ht][1];
            PubB[1][ht * 4 + 2][lane] = oB[ht][2];
            PubB[1][ht * 4 + 3][lane] = oB[ht][3];
        }
        LA[1][lane] = lsA;
        LB[1][lane] = lsB;
    } else {
#pragma unroll
        for (int ht = 0; ht < 4; ++ht) {
            PubA[2][ht * 4 + 0][lane] = oA[ht][0];
            PubA[2][ht * 4 + 1][lane] = oA[ht][1];
            PubA[2][ht * 4 + 2][lane] = oA[ht][2];
            PubA[2][ht * 4 + 3][lane] = oA[ht][3];
            PubB[2][ht * 4 + 0][lane] = oB[ht][0];
            PubB[2][ht * 4 + 1][lane] = oB[ht][1];
            PubB[2][ht * 4 + 2][lane] = oB[ht][2];
            PubB[2][ht * 4 + 3][lane] = oB[ht][3];
        }
        LA[2][lane] = lsA;
        LB[2][lane] = lsB;
    }
    __syncthreads();

    if (wave < 2) {
        f32x4 mo[4];
        float mls;
        if (wave == 0) {
            mo[0] = oA[0]; mo[1] = oA[1]; mo[2] = oA[2]; mo[3] = oA[3];
            mls = lsA;
        } else {
            mo[0] = oB[0]; mo[1] = oB[1]; mo[2] = oB[2]; mo[3] = oB[3];
            mls = lsB;
        }
        const float (*P)[16][64] = (wave == 0) ? PubA : PubB;
        const float (*L)[64]     = (wave == 0) ? LA : LB;
#pragma unroll
        for (int j = 0; j < 3; ++j) {
#pragma unroll
            for (int ht = 0; ht < 4; ++ht) {
                mo[ht][0] += P[j][ht * 4 + 0][lane];
                mo[ht][1] += P[j][ht * 4 + 1][lane];
                mo[ht][2] += P[j][ht * 4 + 2][lane];
                mo[ht][3] += P[j][ht * 4 + 3][lane];
            }
            mls += L[j][lane];
        }

        mls += __shfl_xor(mls, 16, 64);
        mls += __shfl_xor(mls, 32, 64);
        float inv = 1.0f / mls;

        float* orow = out + ((size_t)b * Tseq + qbase + wave * 16 + m) * 64;
        float4 wv;
#pragma unroll
        for (int ht = 0; ht < 4; ++ht) {
            wv.x = mo[ht][0] * inv; wv.y = mo[ht][1] * inv;
            wv.z = mo[ht][2] * inv; wv.w = mo[ht][3] * inv;
            *(float4a*)(orow + ht * 16 + quad * 4) = wv;
        }
    }
}

extern "C" void kernel_launch(void* const* d_in, const int* in_sizes, int n_in,
                              void* d_out, int out_size, void* d_ws, size_t ws_size,
                              hipStream_t stream) {
    const float* x  = (const float*)d_in[0];
    const float* Wq = (const float*)d_in[1];
    const float* Wk = (const float*)d_in[2];
    const float* Wv = (const float*)d_in[3];
    float* out = (float*)d_out;

    char* ws = (char*)d_ws;
    u16* wtf = (u16*)ws;                                       // 384 KiB
    u16* qb  = (u16*)(ws + 512 * 1024);                        // 4 MiB
    u16* kA  = (u16*)(ws + 512 * 1024 + 4 * 1024 * 1024);      // 4 MiB
    u16* vA  = (u16*)(ws + 512 * 1024 + 8 * 1024 * 1024);      // 4 MiB

    wt_kernel<<<96, 256, 0, stream>>>(Wq, Wk, Wv, wtf);
    proj_kernel<<<512, 256, 0, stream>>>(x, wtf, qb, kA, vA);
    attn_kernel<<<1024, 256, 0, stream>>>(qb, kA, vA, out);
}